// Round 5
// baseline (131.980 us; speedup 1.0000x reference)
//
#include <hip/hip_runtime.h>

#define N_SAMPLES 4096
#define DIM 2048
#define NUM_CLASSES 128
#define MARGIN 0.5f

typedef float vfloat4 __attribute__((ext_vector_type(4)));  // native vec for nontemporal builtin

// ---------------- ws layout (byte offsets) ----------------
// cnt   : C ints        @ 0
// meanR : C*D floats    @ 1024
// meanT : C*D floats    @ 1024 + C*D*4

// Kernel 1: per-class means, self-contained (no pre-sort).
// grid (2, C, 2), block 256. Each block scans targets (16 KB, L2-hot),
// compacts its class's rows into LDS, then sums float4 columns with an
// 8-deep row unroll for MLP. Inputs are streamed with non-temporal loads
// (read-once; keeps L2 for targets + means).
__global__ __launch_bounds__(256) void mean_kernel(
        const float* __restrict__ x1,
        const float* __restrict__ x2,
        const int* __restrict__ targets,
        int* __restrict__ cnt,
        float* __restrict__ meanR,
        float* __restrict__ meanT,
        float* __restrict__ d_out, int out_size) {
    __shared__ int s_rows[N_SAMPLES];
    __shared__ int s_n;
    const int tid = threadIdx.x;
    const int c = blockIdx.y;
    const float* __restrict__ x = (blockIdx.z == 0) ? x1 : x2;
    float* __restrict__ mean    = (blockIdx.z == 0) ? meanR : meanT;

    if (tid == 0) s_n = 0;
    if (blockIdx.x == 0 && blockIdx.y == 0 && blockIdx.z == 0) {
        for (int i = tid; i < out_size; i += 256) d_out[i] = 0.0f;  // loss runs after us
    }
    __syncthreads();

    // compact rows of class c (order irrelevant)
    const int4* __restrict__ t4 = (const int4*)targets;
    for (int i = tid; i < N_SAMPLES / 4; i += 256) {
        const int4 v = t4[i];
        const int base = i * 4;
        if (v.x == c) s_rows[atomicAdd(&s_n, 1)] = base;
        if (v.y == c) s_rows[atomicAdd(&s_n, 1)] = base + 1;
        if (v.z == c) s_rows[atomicAdd(&s_n, 1)] = base + 2;
        if (v.w == c) s_rows[atomicAdd(&s_n, 1)] = base + 3;
    }
    __syncthreads();
    const int n = s_n;

    const int col = blockIdx.x * 256 + tid;          // vfloat4 index in [0,512)
    const vfloat4* __restrict__ xs = (const vfloat4*)x;
    vfloat4 acc = {0.0f, 0.0f, 0.0f, 0.0f};
    int k = 0;
    for (; k + 8 <= n; k += 8) {
        vfloat4 v[8];
#pragma unroll
        for (int u = 0; u < 8; ++u) {
            const int r = s_rows[k + u];             // LDS broadcast, free
            v[u] = __builtin_nontemporal_load(&xs[(size_t)r * (DIM / 4) + col]);
        }
#pragma unroll
        for (int u = 0; u < 8; ++u) acc += v[u];
    }
    for (; k < n; ++k) {
        const int r = s_rows[k];
        acc += __builtin_nontemporal_load(&xs[(size_t)r * (DIM / 4) + col]);
    }
    const float inv = 1.0f / (float)((n > 0) ? n : 1);
    acc *= inv;
    ((vfloat4*)mean)[(size_t)c * (DIM / 4) + col] = acc;

    if (blockIdx.x == 0 && blockIdx.z == 0 && tid == 0) cnt[c] = n;
}

// acc += sum((a2 - s)^2) componentwise; caller scales by 0.25 at the end,
// since ||ra - 0.5(rb+tb)||^2 == 0.25 * ||2ra - (rb+tb)||^2.
__device__ __forceinline__ void accum_sq2(float& acc, const float4& a2, const float4& s) {
    float d;
    d = a2.x - s.x; acc = fmaf(d, d, acc);
    d = a2.y - s.y; acc = fmaf(d, d, acc);
    d = a2.z - s.z; acc = fmaf(d, d, acc);
    d = a2.w - s.w; acc = fmaf(d, d, acc);
}

__device__ __forceinline__ float wave_sum64(float v) {
#pragma unroll
    for (int m = 32; m >= 1; m >>= 1) v += __shfl_xor(v, m, 64);
    return v;
}

// Kernel 2: class-pair distances + contrastive terms. One wave per 4a x 4b
// tile -> 1024 waves -> 256 blocks of 256. Means (2 MB) are L2-resident.
__global__ __launch_bounds__(256) void loss_kernel(
        const float* __restrict__ meanR,
        const float* __restrict__ meanT,
        const int* __restrict__ cnt,
        float* __restrict__ d_out) {
    const int gtid = blockIdx.x * blockDim.x + threadIdx.x;
    const int wid  = gtid >> 6;          // 0..1023
    const int lane = threadIdx.x & 63;
    const int a0 = (wid >> 5) * 4;       // a-tile: 4 classes
    const int b0 = (wid & 31) * 4;       // b-tile: 4 classes

    float acc1[4][4], acc2[4][4];
#pragma unroll
    for (int i = 0; i < 4; ++i)
#pragma unroll
        for (int j = 0; j < 4; ++j) { acc1[i][j] = 0.0f; acc2[i][j] = 0.0f; }

    const int ITERS = DIM / 4 / 64;      // 8
#pragma unroll 2
    for (int it = 0; it < ITERS; ++it) {
        const int d = lane + it * 64;    // float4 index within a row
        float4 a2R[4], a2T[4];
#pragma unroll
        for (int i = 0; i < 4; ++i) {
            float4 ra = ((const float4*)(meanR + (size_t)(a0 + i) * DIM))[d];
            float4 ta = ((const float4*)(meanT + (size_t)(a0 + i) * DIM))[d];
            a2R[i].x = ra.x + ra.x; a2R[i].y = ra.y + ra.y;
            a2R[i].z = ra.z + ra.z; a2R[i].w = ra.w + ra.w;
            a2T[i].x = ta.x + ta.x; a2T[i].y = ta.y + ta.y;
            a2T[i].z = ta.z + ta.z; a2T[i].w = ta.w + ta.w;
        }
#pragma unroll
        for (int j = 0; j < 4; ++j) {
            const int b = b0 + j;
            const float4 rb = ((const float4*)(meanR + (size_t)b * DIM))[d];
            const float4 tb = ((const float4*)(meanT + (size_t)b * DIM))[d];
            float4 s;
            s.x = rb.x + tb.x; s.y = rb.y + tb.y;
            s.z = rb.z + tb.z; s.w = rb.w + tb.w;
#pragma unroll
            for (int i = 0; i < 4; ++i) {
                accum_sq2(acc1[i][j], a2R[i], s);
                accum_sq2(acc2[i][j], a2T[i], s);
            }
        }
    }

#pragma unroll
    for (int i = 0; i < 4; ++i)
#pragma unroll
        for (int j = 0; j < 4; ++j) {
            acc1[i][j] = wave_sum64(acc1[i][j]);
            acc2[i][j] = wave_sum64(acc2[i][j]);
        }

    __shared__ float s_part[4];
    if (lane == 0) {
        const float invN2 = 1.0f / ((float)N_SAMPLES * (float)N_SAMPLES);
        float total = 0.0f;
#pragma unroll
        for (int i = 0; i < 4; ++i) {
            const int a = a0 + i;
            const float ca = (float)cnt[a];
#pragma unroll
            for (int j = 0; j < 4; ++j) {
                const int b = b0 + j;
                const float w = ca * (float)cnt[b] * invN2;
                const float sq1 = fmaxf(0.25f * acc1[i][j], 1e-12f);
                const float sq2 = fmaxf(0.25f * acc2[i][j], 1e-12f);
                float t1, t2;
                if (a == b) {
                    t1 = sq1;             // label==1: dist^2 == clamped sq
                    t2 = sq2;
                } else {
                    const float dd1 = sqrtf(sqrtf(sq1) + 1e-10f);
                    const float dd2 = sqrtf(sqrtf(sq2) + 1e-10f);
                    const float r1 = fmaxf(MARGIN - dd1, 0.0f);
                    const float r2 = fmaxf(MARGIN - dd2, 0.0f);
                    t1 = r1 * r1;
                    t2 = r2 * r2;
                }
                total += w * (t1 + t2);
            }
        }
        s_part[threadIdx.x >> 6] = total;
    }
    __syncthreads();
    if (threadIdx.x == 0)
        atomicAdd(d_out, (s_part[0] + s_part[1]) + (s_part[2] + s_part[3]));
}

extern "C" void kernel_launch(void* const* d_in, const int* in_sizes, int n_in,
                              void* d_out, int out_size, void* d_ws, size_t ws_size,
                              hipStream_t stream) {
    const float* modal1 = (const float*)d_in[0];
    const float* modal2 = (const float*)d_in[1];
    const int* targets  = (const int*)d_in[2];
    float* out = (float*)d_out;

    char* ws = (char*)d_ws;
    int*   cnt   = (int*)(ws + 0);
    float* meanR = (float*)(ws + 1024);
    float* meanT = (float*)(ws + 1024 + (size_t)NUM_CLASSES * DIM * 4);

    // 1. per-class means (self-gathering; also zeroes d_out, publishes cnt)
    dim3 gridB(2, NUM_CLASSES, 2);
    mean_kernel<<<gridB, 256, 0, stream>>>(modal1, modal2, targets, cnt,
                                           meanR, meanT, out, out_size);

    // 2. class-pair losses -> scalar (4x4 tiles, 1024 waves)
    const int waves = (NUM_CLASSES / 4) * (NUM_CLASSES / 4);  // 1024
    loss_kernel<<<waves / 4, 256, 0, stream>>>(meanR, meanT, cnt, out);
}

// Round 6
// 125.808 us; speedup vs baseline: 1.0491x; 1.0491x over previous
//
#include <hip/hip_runtime.h>

#define N_SAMPLES 4096
#define DIM 2048
#define NUM_CLASSES 128
#define MARGIN 0.5f

// ---------------- ws layout (byte offsets) ----------------
// cnt   : C ints        @ 0
// meanR : C*D floats    @ 1024
// meanT : C*D floats    @ 1024 + C*D*4

// Kernel 1: per-class means, self-contained (no pre-sort).
// grid (2, C, 2), block 256. Each block scans targets (16 KB, L2-hot),
// compacts its class's rows into LDS, then sums float4 columns with a
// 4-deep row unroll for MLP. Inputs read exactly once across the grid.
// NOTE: plain (cached) float4 loads — nontemporal loads regressed 2x (R5).
__global__ __launch_bounds__(256) void mean_kernel(
        const float* __restrict__ x1,
        const float* __restrict__ x2,
        const int* __restrict__ targets,
        int* __restrict__ cnt,
        float* __restrict__ meanR,
        float* __restrict__ meanT,
        float* __restrict__ d_out, int out_size) {
    __shared__ int s_rows[N_SAMPLES];
    __shared__ int s_n;
    const int tid = threadIdx.x;
    const int c = blockIdx.y;
    const float* __restrict__ x = (blockIdx.z == 0) ? x1 : x2;
    float* __restrict__ mean    = (blockIdx.z == 0) ? meanR : meanT;

    if (tid == 0) s_n = 0;
    if (blockIdx.x == 0 && blockIdx.y == 0 && blockIdx.z == 0) {
        for (int i = tid; i < out_size; i += 256) d_out[i] = 0.0f;  // loss runs after us
    }
    __syncthreads();

    // compact rows of class c (order irrelevant)
    const int4* __restrict__ t4 = (const int4*)targets;
    for (int i = tid; i < N_SAMPLES / 4; i += 256) {
        const int4 v = t4[i];
        const int base = i * 4;
        if (v.x == c) s_rows[atomicAdd(&s_n, 1)] = base;
        if (v.y == c) s_rows[atomicAdd(&s_n, 1)] = base + 1;
        if (v.z == c) s_rows[atomicAdd(&s_n, 1)] = base + 2;
        if (v.w == c) s_rows[atomicAdd(&s_n, 1)] = base + 3;
    }
    __syncthreads();
    const int n = s_n;

    const int col = blockIdx.x * 256 + tid;          // float4 index in [0,512)
    const float4* __restrict__ xs = (const float4*)x;
    float ax = 0.0f, ay = 0.0f, az = 0.0f, aw = 0.0f;
    int k = 0;
    for (; k + 4 <= n; k += 4) {
        const int r0 = s_rows[k + 0];                // LDS broadcast, free
        const int r1 = s_rows[k + 1];
        const int r2 = s_rows[k + 2];
        const int r3 = s_rows[k + 3];
        const float4 v0 = xs[(size_t)r0 * (DIM / 4) + col];
        const float4 v1 = xs[(size_t)r1 * (DIM / 4) + col];
        const float4 v2 = xs[(size_t)r2 * (DIM / 4) + col];
        const float4 v3 = xs[(size_t)r3 * (DIM / 4) + col];
        ax += (v0.x + v1.x) + (v2.x + v3.x);
        ay += (v0.y + v1.y) + (v2.y + v3.y);
        az += (v0.z + v1.z) + (v2.z + v3.z);
        aw += (v0.w + v1.w) + (v2.w + v3.w);
    }
    for (; k < n; ++k) {
        const int r = s_rows[k];
        const float4 v = xs[(size_t)r * (DIM / 4) + col];
        ax += v.x; ay += v.y; az += v.z; aw += v.w;
    }
    const float inv = 1.0f / (float)((n > 0) ? n : 1);
    float4 m; m.x = ax * inv; m.y = ay * inv; m.z = az * inv; m.w = aw * inv;
    ((float4*)mean)[(size_t)c * (DIM / 4) + col] = m;

    if (blockIdx.x == 0 && blockIdx.z == 0 && tid == 0) cnt[c] = n;
}

// acc += sum((a2 - s)^2) componentwise; caller scales by 0.25 at the end,
// since ||ra - 0.5(rb+tb)||^2 == 0.25 * ||2ra - (rb+tb)||^2.
__device__ __forceinline__ void accum_sq2(float& acc, const float4& a2, const float4& s) {
    float d;
    d = a2.x - s.x; acc = fmaf(d, d, acc);
    d = a2.y - s.y; acc = fmaf(d, d, acc);
    d = a2.z - s.z; acc = fmaf(d, d, acc);
    d = a2.w - s.w; acc = fmaf(d, d, acc);
}

__device__ __forceinline__ float wave_sum64(float v) {
#pragma unroll
    for (int m = 32; m >= 1; m >>= 1) v += __shfl_xor(v, m, 64);
    return v;
}

// Kernel 2: class-pair distances + contrastive terms. One wave per 4a x 4b
// tile -> 1024 waves -> 256 blocks of 256. Means (2 MB) are L2-resident.
__global__ __launch_bounds__(256) void loss_kernel(
        const float* __restrict__ meanR,
        const float* __restrict__ meanT,
        const int* __restrict__ cnt,
        float* __restrict__ d_out) {
    const int gtid = blockIdx.x * blockDim.x + threadIdx.x;
    const int wid  = gtid >> 6;          // 0..1023
    const int lane = threadIdx.x & 63;
    const int a0 = (wid >> 5) * 4;       // a-tile: 4 classes
    const int b0 = (wid & 31) * 4;       // b-tile: 4 classes

    float acc1[4][4], acc2[4][4];
#pragma unroll
    for (int i = 0; i < 4; ++i)
#pragma unroll
        for (int j = 0; j < 4; ++j) { acc1[i][j] = 0.0f; acc2[i][j] = 0.0f; }

    const int ITERS = DIM / 4 / 64;      // 8
#pragma unroll 2
    for (int it = 0; it < ITERS; ++it) {
        const int d = lane + it * 64;    // float4 index within a row
        float4 a2R[4], a2T[4];
#pragma unroll
        for (int i = 0; i < 4; ++i) {
            float4 ra = ((const float4*)(meanR + (size_t)(a0 + i) * DIM))[d];
            float4 ta = ((const float4*)(meanT + (size_t)(a0 + i) * DIM))[d];
            a2R[i].x = ra.x + ra.x; a2R[i].y = ra.y + ra.y;
            a2R[i].z = ra.z + ra.z; a2R[i].w = ra.w + ra.w;
            a2T[i].x = ta.x + ta.x; a2T[i].y = ta.y + ta.y;
            a2T[i].z = ta.z + ta.z; a2T[i].w = ta.w + ta.w;
        }
#pragma unroll
        for (int j = 0; j < 4; ++j) {
            const int b = b0 + j;
            const float4 rb = ((const float4*)(meanR + (size_t)b * DIM))[d];
            const float4 tb = ((const float4*)(meanT + (size_t)b * DIM))[d];
            float4 s;
            s.x = rb.x + tb.x; s.y = rb.y + tb.y;
            s.z = rb.z + tb.z; s.w = rb.w + tb.w;
#pragma unroll
            for (int i = 0; i < 4; ++i) {
                accum_sq2(acc1[i][j], a2R[i], s);
                accum_sq2(acc2[i][j], a2T[i], s);
            }
        }
    }

#pragma unroll
    for (int i = 0; i < 4; ++i)
#pragma unroll
        for (int j = 0; j < 4; ++j) {
            acc1[i][j] = wave_sum64(acc1[i][j]);
            acc2[i][j] = wave_sum64(acc2[i][j]);
        }

    __shared__ float s_part[4];
    if (lane == 0) {
        const float invN2 = 1.0f / ((float)N_SAMPLES * (float)N_SAMPLES);
        float total = 0.0f;
#pragma unroll
        for (int i = 0; i < 4; ++i) {
            const int a = a0 + i;
            const float ca = (float)cnt[a];
#pragma unroll
            for (int j = 0; j < 4; ++j) {
                const int b = b0 + j;
                const float w = ca * (float)cnt[b] * invN2;
                const float sq1 = fmaxf(0.25f * acc1[i][j], 1e-12f);
                const float sq2 = fmaxf(0.25f * acc2[i][j], 1e-12f);
                float t1, t2;
                if (a == b) {
                    t1 = sq1;             // label==1: dist^2 == clamped sq
                    t2 = sq2;
                } else {
                    const float dd1 = sqrtf(sqrtf(sq1) + 1e-10f);
                    const float dd2 = sqrtf(sqrtf(sq2) + 1e-10f);
                    const float r1 = fmaxf(MARGIN - dd1, 0.0f);
                    const float r2 = fmaxf(MARGIN - dd2, 0.0f);
                    t1 = r1 * r1;
                    t2 = r2 * r2;
                }
                total += w * (t1 + t2);
            }
        }
        s_part[threadIdx.x >> 6] = total;
    }
    __syncthreads();
    if (threadIdx.x == 0)
        atomicAdd(d_out, (s_part[0] + s_part[1]) + (s_part[2] + s_part[3]));
}

extern "C" void kernel_launch(void* const* d_in, const int* in_sizes, int n_in,
                              void* d_out, int out_size, void* d_ws, size_t ws_size,
                              hipStream_t stream) {
    const float* modal1 = (const float*)d_in[0];
    const float* modal2 = (const float*)d_in[1];
    const int* targets  = (const int*)d_in[2];
    float* out = (float*)d_out;

    char* ws = (char*)d_ws;
    int*   cnt   = (int*)(ws + 0);
    float* meanR = (float*)(ws + 1024);
    float* meanT = (float*)(ws + 1024 + (size_t)NUM_CLASSES * DIM * 4);

    // 1. per-class means (self-gathering; also zeroes d_out, publishes cnt)
    dim3 gridB(2, NUM_CLASSES, 2);
    mean_kernel<<<gridB, 256, 0, stream>>>(modal1, modal2, targets, cnt,
                                           meanR, meanT, out, out_size);

    // 2. class-pair losses -> scalar (4x4 tiles, 1024 waves)
    const int waves = (NUM_CLASSES / 4) * (NUM_CLASSES / 4);  // 1024
    loss_kernel<<<waves / 4, 256, 0, stream>>>(meanR, meanT, cnt, out);
}

// Round 7
// 118.074 us; speedup vs baseline: 1.1178x; 1.0655x over previous
//
#include <hip/hip_runtime.h>

#define N_SAMPLES 4096
#define DIM 2048
#define NUM_CLASSES 128
#define MARGIN 0.5f

// ---------------- ws layout (byte offsets) ----------------
// cnt   : C ints        @ 0
// meanR : C*D floats    @ 1024
// meanT : C*D floats    @ 1024 + C*D*4
//
// R7 = exact revert to R3 (best measured: 118.8 us).
// R5 (nontemporal loads + 8-deep unroll in mean): +13 us — regression.
// R6 (loss algebraic refactor only): +7 us vs R3 — regression/noise; reverted.

// Kernel 1: per-class means, self-contained (no pre-sort).
// grid (2, C, 2), block 256. Each block scans targets (16 KB, L2-hot),
// compacts its class's rows into LDS, then sums float4 columns with a
// 4-deep row unroll for MLP. Inputs read exactly once across the grid.
__global__ __launch_bounds__(256) void mean_kernel(
        const float* __restrict__ x1,
        const float* __restrict__ x2,
        const int* __restrict__ targets,
        int* __restrict__ cnt,
        float* __restrict__ meanR,
        float* __restrict__ meanT,
        float* __restrict__ d_out, int out_size) {
    __shared__ int s_rows[N_SAMPLES];
    __shared__ int s_n;
    const int tid = threadIdx.x;
    const int c = blockIdx.y;
    const float* __restrict__ x = (blockIdx.z == 0) ? x1 : x2;
    float* __restrict__ mean    = (blockIdx.z == 0) ? meanR : meanT;

    if (tid == 0) s_n = 0;
    if (blockIdx.x == 0 && blockIdx.y == 0 && blockIdx.z == 0) {
        for (int i = tid; i < out_size; i += 256) d_out[i] = 0.0f;  // loss runs after us
    }
    __syncthreads();

    // compact rows of class c (order irrelevant)
    const int4* __restrict__ t4 = (const int4*)targets;
    for (int i = tid; i < N_SAMPLES / 4; i += 256) {
        const int4 v = t4[i];
        const int base = i * 4;
        if (v.x == c) s_rows[atomicAdd(&s_n, 1)] = base;
        if (v.y == c) s_rows[atomicAdd(&s_n, 1)] = base + 1;
        if (v.z == c) s_rows[atomicAdd(&s_n, 1)] = base + 2;
        if (v.w == c) s_rows[atomicAdd(&s_n, 1)] = base + 3;
    }
    __syncthreads();
    const int n = s_n;

    const int col = blockIdx.x * 256 + tid;          // float4 index in [0,512)
    const float4* __restrict__ xs = (const float4*)x;
    float ax = 0.0f, ay = 0.0f, az = 0.0f, aw = 0.0f;
    int k = 0;
    for (; k + 4 <= n; k += 4) {
        const int r0 = s_rows[k + 0];                // LDS broadcast, free
        const int r1 = s_rows[k + 1];
        const int r2 = s_rows[k + 2];
        const int r3 = s_rows[k + 3];
        const float4 v0 = xs[(size_t)r0 * (DIM / 4) + col];
        const float4 v1 = xs[(size_t)r1 * (DIM / 4) + col];
        const float4 v2 = xs[(size_t)r2 * (DIM / 4) + col];
        const float4 v3 = xs[(size_t)r3 * (DIM / 4) + col];
        ax += (v0.x + v1.x) + (v2.x + v3.x);
        ay += (v0.y + v1.y) + (v2.y + v3.y);
        az += (v0.z + v1.z) + (v2.z + v3.z);
        aw += (v0.w + v1.w) + (v2.w + v3.w);
    }
    for (; k < n; ++k) {
        const int r = s_rows[k];
        const float4 v = xs[(size_t)r * (DIM / 4) + col];
        ax += v.x; ay += v.y; az += v.z; aw += v.w;
    }
    const float inv = 1.0f / (float)((n > 0) ? n : 1);
    float4 m; m.x = ax * inv; m.y = ay * inv; m.z = az * inv; m.w = aw * inv;
    ((float4*)mean)[(size_t)c * (DIM / 4) + col] = m;

    if (blockIdx.x == 0 && blockIdx.z == 0 && tid == 0) cnt[c] = n;
}

__device__ __forceinline__ void accum_sq(float& acc, const float4& a, const float4& c) {
    float d;
    d = a.x - c.x; acc = fmaf(d, d, acc);
    d = a.y - c.y; acc = fmaf(d, d, acc);
    d = a.z - c.z; acc = fmaf(d, d, acc);
    d = a.w - c.w; acc = fmaf(d, d, acc);
}

__device__ __forceinline__ float wave_sum64(float v) {
#pragma unroll
    for (int m = 32; m >= 1; m >>= 1) v += __shfl_xor(v, m, 64);
    return v;
}

// Kernel 2: class-pair distances + contrastive terms. One wave per 4a x 4b
// tile -> 1024 waves -> 256 blocks of 256. Means (2 MB) are L2-resident.
__global__ __launch_bounds__(256) void loss_kernel(
        const float* __restrict__ meanR,
        const float* __restrict__ meanT,
        const int* __restrict__ cnt,
        float* __restrict__ d_out) {
    const int gtid = blockIdx.x * blockDim.x + threadIdx.x;
    const int wid  = gtid >> 6;          // 0..1023
    const int lane = threadIdx.x & 63;
    const int a0 = (wid >> 5) * 4;       // a-tile: 4 classes
    const int b0 = (wid & 31) * 4;       // b-tile: 4 classes

    float acc1[4][4], acc2[4][4];
#pragma unroll
    for (int i = 0; i < 4; ++i)
#pragma unroll
        for (int j = 0; j < 4; ++j) { acc1[i][j] = 0.0f; acc2[i][j] = 0.0f; }

    const int ITERS = DIM / 4 / 64;      // 8
#pragma unroll 2
    for (int it = 0; it < ITERS; ++it) {
        const int d = lane + it * 64;    // float4 index within a row
        float4 ra[4], ta[4];
#pragma unroll
        for (int i = 0; i < 4; ++i) {
            ra[i] = ((const float4*)(meanR + (size_t)(a0 + i) * DIM))[d];
            ta[i] = ((const float4*)(meanT + (size_t)(a0 + i) * DIM))[d];
        }
#pragma unroll
        for (int j = 0; j < 4; ++j) {
            const int b = b0 + j;
            const float4 rb = ((const float4*)(meanR + (size_t)b * DIM))[d];
            const float4 tb = ((const float4*)(meanT + (size_t)b * DIM))[d];
            float4 cb;
            cb.x = 0.5f * (rb.x + tb.x);
            cb.y = 0.5f * (rb.y + tb.y);
            cb.z = 0.5f * (rb.z + tb.z);
            cb.w = 0.5f * (rb.w + tb.w);
#pragma unroll
            for (int i = 0; i < 4; ++i) {
                accum_sq(acc1[i][j], ra[i], cb);
                accum_sq(acc2[i][j], ta[i], cb);
            }
        }
    }

#pragma unroll
    for (int i = 0; i < 4; ++i)
#pragma unroll
        for (int j = 0; j < 4; ++j) {
            acc1[i][j] = wave_sum64(acc1[i][j]);
            acc2[i][j] = wave_sum64(acc2[i][j]);
        }

    __shared__ float s_part[4];
    if (lane == 0) {
        const float invN2 = 1.0f / ((float)N_SAMPLES * (float)N_SAMPLES);
        float total = 0.0f;
#pragma unroll
        for (int i = 0; i < 4; ++i) {
            const int a = a0 + i;
            const float ca = (float)cnt[a];
#pragma unroll
            for (int j = 0; j < 4; ++j) {
                const int b = b0 + j;
                const float w = ca * (float)cnt[b] * invN2;
                const float sq1 = fmaxf(acc1[i][j], 1e-12f);
                const float sq2 = fmaxf(acc2[i][j], 1e-12f);
                float t1, t2;
                if (a == b) {
                    t1 = sq1;             // label==1: d2^2 == clamped sq
                    t2 = sq2;
                } else {
                    const float dd1 = sqrtf(sqrtf(sq1) + 1e-10f);
                    const float dd2 = sqrtf(sqrtf(sq2) + 1e-10f);
                    const float r1 = fmaxf(MARGIN - dd1, 0.0f);
                    const float r2 = fmaxf(MARGIN - dd2, 0.0f);
                    t1 = r1 * r1;
                    t2 = r2 * r2;
                }
                total += w * (t1 + t2);
            }
        }
        s_part[threadIdx.x >> 6] = total;
    }
    __syncthreads();
    if (threadIdx.x == 0)
        atomicAdd(d_out, (s_part[0] + s_part[1]) + (s_part[2] + s_part[3]));
}

extern "C" void kernel_launch(void* const* d_in, const int* in_sizes, int n_in,
                              void* d_out, int out_size, void* d_ws, size_t ws_size,
                              hipStream_t stream) {
    const float* modal1 = (const float*)d_in[0];
    const float* modal2 = (const float*)d_in[1];
    const int* targets  = (const int*)d_in[2];
    float* out = (float*)d_out;

    char* ws = (char*)d_ws;
    int*   cnt   = (int*)(ws + 0);
    float* meanR = (float*)(ws + 1024);
    float* meanT = (float*)(ws + 1024 + (size_t)NUM_CLASSES * DIM * 4);

    // 1. per-class means (self-gathering; also zeroes d_out, publishes cnt)
    dim3 gridB(2, NUM_CLASSES, 2);
    mean_kernel<<<gridB, 256, 0, stream>>>(modal1, modal2, targets, cnt,
                                           meanR, meanT, out, out_size);

    // 2. class-pair losses -> scalar (4x4 tiles, 1024 waves)
    const int waves = (NUM_CLASSES / 4) * (NUM_CLASSES / 4);  // 1024
    loss_kernel<<<waves / 4, 256, 0, stream>>>(meanR, meanT, cnt, out);
}